// Round 17
// baseline (337.026 us; speedup 1.0000x reference)
//
#include <hip/hip_runtime.h>
#include <hip/hip_fp16.h>

typedef _Float16 f16;
typedef _Float16 f16x4 __attribute__((ext_vector_type(4)));
typedef _Float16 f16x8 __attribute__((ext_vector_type(8)));
typedef float f32x4 __attribute__((ext_vector_type(4)));
typedef float f32x16 __attribute__((ext_vector_type(16)));
typedef unsigned int u32;
typedef u32 u32x4 __attribute__((ext_vector_type(4)));

static constexpr int CB = 8;      // batch
static constexpr int CC = 256;    // channels = Co
static constexpr int CN = 4096;   // tokens = H*W

#define MFMA(a, b, c)   __builtin_amdgcn_mfma_f32_16x16x32_f16((a), (b), (c), 0, 0, 0)
#define MFMA32(a, b, c) __builtin_amdgcn_mfma_f32_32x32x16_f16((a), (b), (c), 0, 0, 0)

__device__ __forceinline__ void gll16(const void* g, void* l) {
  __builtin_amdgcn_global_load_lds(
      (const __attribute__((address_space(1))) unsigned int*)g,
      (__attribute__((address_space(3))) unsigned int*)l, 16, 0, 0);
}

// swap a's lanes 32-63 with b's lanes 0-31 (CDNA4 cross-half exchange)
__device__ __forceinline__ void plswap(u32& a, u32& b) {
  asm volatile("v_permlane32_swap_b32 %0, %1" : "+v"(a), "+v"(b));
}

__device__ __forceinline__ u32 pk(float lo, float hi) {
  auto h = __builtin_amdgcn_cvt_pkrtz(lo, hi);   // __fp16 ext_vector_type(2)
  return __builtin_bit_cast(u32, h);
}

__global__ __launch_bounds__(256) void prep_weights(const float* __restrict__ wq,
    const float* __restrict__ wk, const float* __restrict__ wv,
    const float* __restrict__ wo, f16* __restrict__ W) {
  int i = blockIdx.x * 256 + threadIdx.x;
  W[i]          = (f16)wq[i];
  W[65536 + i]  = (f16)wk[i];
  W[131072 + i] = (f16)wv[i];
  W[196608 + i] = (f16)wo[i];
}

// qkv v3 (verified): 32x32x16 MFMA, 32 n-rows per wave -> weight L2 traffic
// halves vs 16-row waves. Q/K: D[o][n]=mfma(W,x); V: D[n][o]=mfma(x,W).
__global__ __launch_bounds__(128) void qkv_kernel(const float* __restrict__ x,
    const f16* __restrict__ Wq, const f16* __restrict__ Wk, const f16* __restrict__ Wv,
    const float* __restrict__ bq, const float* __restrict__ bk, const float* __restrict__ bv,
    f16* __restrict__ Q, f16* __restrict__ K, f16* __restrict__ Vt) {
  __shared__ f16 xf[64][264];
  const int b  = blockIdx.x >> 6;
  const int n0 = (blockIdx.x & 63) << 6;
  const int t  = threadIdx.x;
  const float* xb = x + (size_t)b * CC * CN;
  {
    int c = t >> 4;                         // 0..7
    const int nn = (t & 15) << 2;
    #pragma unroll
    for (int pass = 0; pass < 32; ++pass, c += 8) {
      const float4 v = *(const float4*)(xb + (size_t)c * CN + n0 + nn);
      xf[nn + 0][c] = (f16)v.x;
      xf[nn + 1][c] = (f16)v.y;
      xf[nn + 2][c] = (f16)v.z;
      xf[nn + 3][c] = (f16)v.w;
    }
  }
  __syncthreads();
  const int w = t >> 6, l = t & 63, ln = l & 31, lh = l >> 5;

  // B-fragment of 32x32x16: lane row = ln (n), k = kt*16 + 8*lh + e
  f16x8 xff[16];
  #pragma unroll
  for (int kt = 0; kt < 16; ++kt)
    xff[kt] = *(const f16x8*)&xf[w * 32 + ln][kt * 16 + lh * 8];

  const size_t qkrow = ((size_t)b * CN + n0 + w * 32 + ln) * CC;

  #pragma unroll 1
  for (int mat = 0; mat < 2; ++mat) {
    const f16* W = mat ? Wk : Wq;
    const float* bias = mat ? bk : bq;
    f16* dst = mat ? K : Q;
    #pragma unroll 1
    for (int ot = 0; ot < 8; ot += 2) {
      f32x16 a0, a1;
      #pragma unroll
      for (int i = 0; i < 16; ++i) { a0[i] = 0.0f; a1[i] = 0.0f; }
      #pragma unroll
      for (int kt = 0; kt < 16; ++kt) {
        const f16x8 af0 = *(const f16x8*)&W[(size_t)(ot * 32 + ln) * CC + kt * 16 + lh * 8];
        a0 = MFMA32(af0, xff[kt], a0);
        const f16x8 af1 = *(const f16x8*)&W[(size_t)(ot * 32 + 32 + ln) * CC + kt * 16 + lh * 8];
        a1 = MFMA32(af1, xff[kt], a1);
      }
      #pragma unroll
      for (int rg = 0; rg < 4; ++rg) {
        const int o = ot * 32 + rg * 8 + lh * 4;
        const float4 b0 = *(const float4*)&bias[o];
        const float4 b1 = *(const float4*)&bias[o + 32];
        f16x4 h0, h1;
        h0[0] = (f16)(a0[rg * 4 + 0] + b0.x);
        h0[1] = (f16)(a0[rg * 4 + 1] + b0.y);
        h0[2] = (f16)(a0[rg * 4 + 2] + b0.z);
        h0[3] = (f16)(a0[rg * 4 + 3] + b0.w);
        h1[0] = (f16)(a1[rg * 4 + 0] + b1.x);
        h1[1] = (f16)(a1[rg * 4 + 1] + b1.y);
        h1[2] = (f16)(a1[rg * 4 + 2] + b1.z);
        h1[3] = (f16)(a1[rg * 4 + 3] + b1.w);
        *(f16x4*)&dst[qkrow + o]      = h0;
        *(f16x4*)&dst[qkrow + o + 32] = h1;
      }
    }
  }

  #pragma unroll 1
  for (int ot = 0; ot < 8; ot += 2) {
    f32x16 a0, a1;
    #pragma unroll
    for (int i = 0; i < 16; ++i) { a0[i] = 0.0f; a1[i] = 0.0f; }
    #pragma unroll
    for (int kt = 0; kt < 16; ++kt) {
      const f16x8 wf0 = *(const f16x8*)&Wv[(size_t)(ot * 32 + ln) * CC + kt * 16 + lh * 8];
      a0 = MFMA32(xff[kt], wf0, a0);
      const f16x8 wf1 = *(const f16x8*)&Wv[(size_t)(ot * 32 + 32 + ln) * CC + kt * 16 + lh * 8];
      a1 = MFMA32(xff[kt], wf1, a1);
    }
    const int o0 = ot * 32 + ln, o1 = o0 + 32;
    const float bv0 = bv[o0], bv1 = bv[o1];
    f16* v0 = &Vt[((size_t)b * CC + o0) * CN + n0 + w * 32];
    f16* v1 = &Vt[((size_t)b * CC + o1) * CN + n0 + w * 32];
    #pragma unroll
    for (int rg = 0; rg < 4; ++rg) {
      const int nn = rg * 8 + lh * 4;
      f16x4 h0, h1;
      #pragma unroll
      for (int j = 0; j < 4; ++j) {
        h0[j] = (f16)(a0[rg * 4 + j] + bv0);
        h1[j] = (f16)(a1[rg * 4 + j] + bv1);
      }
      *(f16x4*)&v0[nn] = h0;
      *(f16x4*)&v1[nn] = h1;
    }
  }
}

// flash attention v14: EXACT v11 main loop (single 16-deep QK chain, no parity
// desync — measured 272.9 us standalone) + r12's fused out-projection epilogue.
// Q,K [B,N,256], V^T [B,256,N], Wo [256,256] -> out [B,C,N] fp32
__global__ __launch_bounds__(256, 2) void attn_kernel(const f16* __restrict__ Q,
    const f16* __restrict__ K, const f16* __restrict__ Vt,
    const f16* __restrict__ Wo, const float* __restrict__ bo,
    float* __restrict__ out) {
  // SMEM (bytes):
  //   [0, 32768):     K frames: buf*16384 + ks*1024 (frag-linear, +16*l)
  //   [32768, 65536): V frames: 32768 + buf*16384 + f*1024
  //   [65536, 73728): P dbuf:   65536 + pbuf*4096 + g*2048 + fr*1024 (+16*l)
  //   [73728, 74240): ML per g: g*256 + {m[32] @0, l[32] @128}  (single-buffered)
  //   [74240, 75264): AF dbuf:  74240 + pbuf*512 + g*256 + {alpha[32] @0, flag @128}
  //   epilogue reuse: [0, 33792) = O-tile [64][264] f16 (2-way banks)
  __shared__ __align__(16) char SMEM[75264];

  const int bid = blockIdx.x;
  const int lb = ((bid & 7) << 6) | (bid >> 3);   // XCD swizzle: batch -> XCD
  const int b  = lb >> 6;
  const int q0 = (lb & 63) << 6;                  // 64 q-rows per block
  const int tid = threadIdx.x;
  const int w  = tid >> 6, l = tid & 63, ln = l & 31, lh = l >> 5;
  const int g  = w >> 1, hv = w & 1;              // q-group, o-half

  const f16* Qb = Q  + (size_t)b * CN * CC;
  const f16* Kb = K  + (size_t)b * CN * CC;
  const f16* Vb = Vt + (size_t)b * CC * CN;

  auto kfrm = [&](int buf, int ks) -> char* { return SMEM + (buf << 14) + (ks << 10); };
  auto vfrm = [&](int buf, int f)  -> char* { return SMEM + 32768 + (buf << 14) + (f << 10); };
  auto pfrm = [&](int pb, int fr)  -> char* { return SMEM + 65536 + (pb << 12) + (g << 11) + (fr << 10); };
  float* const MLm = (float*)(SMEM + 73728 + g * 256);
  float* const MLl = MLm + 32;
  auto AFa = [&](int pb) -> float* { return (float*)(SMEM + 74240 + (pb << 9) + (g << 8)); };

  auto stageK = [&](int buf, int kv0) {
    const f16* ksrc = Kb + (size_t)(kv0 + ln) * CC + (w * 4) * 16 + 8 * lh;
    #pragma unroll
    for (int j = 0; j < 4; ++j)
      gll16(ksrc + j * 16, kfrm(buf, w * 4 + j));
  };
  auto stageV = [&](int buf, int kv0) {
    #pragma unroll
    for (int p = 0; p < 2; ++p) {
      const int f = w * 4 + 2 * p;
      const f16* vsrc = Vb + (size_t)((f >> 1) * 32 + ln) * CN + kv0 + 8 * lh;
      gll16(vsrc,      vfrm(buf, f));
      gll16(vsrc + 16, vfrm(buf, f + 1));
    }
  };

  const int qrow = q0 + 32 * g + ln;
  f16x8 qf[16];
  #pragma unroll
  for (int ks = 0; ks < 16; ++ks)
    qf[ks] = *(const f16x8*)(Qb + (size_t)qrow * CC + ks * 16 + 8 * lh);

  f32x16 oacc[4];
  #pragma unroll
  for (int ot = 0; ot < 4; ++ot)
    #pragma unroll
    for (int i = 0; i < 16; ++i) oacc[ot][i] = 0.0f;

  auto pvstep = [&](int pb) {
    const float* af = AFa(pb);
    const float flag = af[32];
    if (flag != 0.0f) {
      #pragma unroll
      for (int r = 0; r < 16; ++r) {
        const float fr = af[(r & 3) + 8 * (r >> 2) + 4 * lh];
        #pragma unroll
        for (int ot = 0; ot < 4; ++ot) oacc[ot][r] *= fr;
      }
    }
    const f16x8 pa0 = *(const f16x8*)(pfrm(pb, 0) + l * 16);
    const f16x8 pa1 = *(const f16x8*)(pfrm(pb, 1) + l * 16);
    __builtin_amdgcn_s_setprio(1);
    #pragma unroll
    for (int ot = 0; ot < 4; ++ot) {
      const int f0 = 8 * hv + 2 * ot;
      const f16x8 v0 = *(const f16x8*)(vfrm(pb, f0) + l * 16);
      oacc[ot] = MFMA32(pa0, v0, oacc[ot]);
      const f16x8 v1 = *(const f16x8*)(vfrm(pb, f0 + 1) + l * 16);
      oacc[ot] = MFMA32(pa1, v1, oacc[ot]);
    }
    __builtin_amdgcn_s_setprio(0);
  };

  stageK(0, 0);
  __syncthreads();                                // K(0) ready

  #pragma unroll 1
  for (int it = 0; it < 128; ++it) {
    const int cur = it & 1, prv = cur ^ 1;
    if (it < 127) stageK(prv, (it + 1) * 32);     // K(it+1), drained at barrier
    stageV(cur, it * 32);                         // V(it), read next iter

    const bool own = (hv == cur);                 // wave-uniform (v11 exact)

    // owner: QK(it) — single 16-deep MFMA chain (v11 exact)
    f32x16 s;
    if (own) {
      #pragma unroll
      for (int i = 0; i < 16; ++i) s[i] = 0.0f;
      __builtin_amdgcn_s_setprio(1);
      #pragma unroll
      for (int ks = 0; ks < 16; ++ks) {
        const f16x8 kf = *(const f16x8*)(kfrm(cur, ks) + l * 16);
        s = MFMA32(kf, qf[ks], s);
      }
      __builtin_amdgcn_s_setprio(0);
    }

    // all waves: PV(it-1)
    if (it > 0) pvstep(prv);

    // owner: softmax(it) + publish P/alpha/m/l (v11 exact)
    if (own) {
      const float mprev = it ? MLm[ln] : -3e38f;
      const float lprev = it ? MLl[ln] : 0.0f;
      float mx8[8], mx4[4];
      #pragma unroll
      for (int i = 0; i < 8; ++i) mx8[i] = fmaxf(s[2 * i], s[2 * i + 1]);
      #pragma unroll
      for (int i = 0; i < 4; ++i) mx4[i] = fmaxf(mx8[2 * i], mx8[2 * i + 1]);
      float pmax = fmaxf(fmaxf(mx4[0], mx4[1]), fmaxf(mx4[2], mx4[3]));
      pmax = fmaxf(pmax, __shfl_xor(pmax, 32));
      const bool need = !__all(pmax - mprev <= 8.0f);   // defer-max (T13)
      const float mnew = need ? fmaxf(mprev, pmax) : mprev;
      float p[16];
      #pragma unroll
      for (int r = 0; r < 16; ++r) p[r] = __expf(s[r] - mnew);
      float sm8[8], sm4[4];
      #pragma unroll
      for (int i = 0; i < 8; ++i) sm8[i] = p[2 * i] + p[2 * i + 1];
      #pragma unroll
      for (int i = 0; i < 4; ++i) sm4[i] = sm8[2 * i] + sm8[2 * i + 1];
      float psum = (sm4[0] + sm4[1]) + (sm4[2] + sm4[3]);
      psum += __shfl_xor(psum, 32);
      float alpha = 1.0f, lnew;
      if (need) { alpha = __expf(mprev - mnew); lnew = lprev * alpha + psum; }
      else      { lnew = lprev + psum; }
      if (l < 32) {
        MLm[ln] = mnew;
        MLl[ln] = lnew;
        float* af = AFa(cur);
        af[ln] = alpha;
        if (ln == 0) af[32] = need ? 1.0f : 0.0f;
      }
      u32 pw[8];
      #pragma unroll
      for (int i = 0; i < 8; ++i) pw[i] = pk(p[2 * i], p[2 * i + 1]);
      plswap(pw[0], pw[2]); plswap(pw[1], pw[3]);
      plswap(pw[4], pw[6]); plswap(pw[5], pw[7]);
      *(u32x4*)(pfrm(cur, 0) + l * 16) = u32x4{pw[0], pw[1], pw[2], pw[3]};
      *(u32x4*)(pfrm(cur, 1) + l * 16) = u32x4{pw[4], pw[5], pw[6], pw[7]};
    }
    __syncthreads();   // drains K(it+1)/V(it); publishes P/ML/AF(it)
  }

  // epilogue part 1: PV(127) (buffers pb=1), grab 1/l values
  pvstep(1);
  float invv[16];
  #pragma unroll
  for (int r = 0; r < 16; ++r)
    invv[r] = 1.0f / MLl[(r & 3) + 8 * (r >> 2) + 4 * lh];
  __syncthreads();                                // everyone done with K/ML regions

  // epilogue part 2: normalized O-tile -> LDS [64][264] f16
  f16* const OT = (f16*)SMEM;
  #pragma unroll
  for (int r = 0; r < 16; ++r) {
    const int q = (r & 3) + 8 * (r >> 2) + 4 * lh;
    const int qq = 32 * g + q;
    #pragma unroll
    for (int ot = 0; ot < 4; ++ot)
      OT[qq * 264 + 128 * hv + ot * 32 + ln] = (f16)(oacc[ot][r] * invv[r]);
  }
  __syncthreads();

  // epilogue part 3: fused out-projection (verified oproj body, bf from LDS)
  {
    const int lr = l & 15, lq = l >> 4;           // 16x4 lane split
    const f16* orow = OT + (w * 16 + lr) * 264;
    f32x4 acc[16];
    #pragma unroll
    for (int m = 0; m < 16; ++m) acc[m] = f32x4{0.f, 0.f, 0.f, 0.f};
    #pragma unroll
    for (int kk = 0; kk < 8; ++kk) {
      const f16x8 bf = *(const f16x8*)&orow[kk * 32 + lq * 8];
      #pragma unroll
      for (int m = 0; m < 16; ++m) {
        f16x8 af = *(const f16x8*)&Wo[(size_t)(m * 16 + lr) * CC + kk * 32 + lq * 8];
        acc[m] = MFMA(af, bf, acc[m]);
      }
    }
    #pragma unroll
    for (int m = 0; m < 16; ++m) {
      const int c = m * 16 + lq * 4;
      const float4 bv4 = *(const float4*)&bo[c];
      const size_t base = ((size_t)b * CC + c) * CN + q0 + w * 16 + lr;
      out[base + 0 * (size_t)CN] = acc[m][0] + bv4.x;
      out[base + 1 * (size_t)CN] = acc[m][1] + bv4.y;
      out[base + 2 * (size_t)CN] = acc[m][2] + bv4.z;
      out[base + 3 * (size_t)CN] = acc[m][3] + bv4.w;
    }
  }
}

extern "C" void kernel_launch(void* const* d_in, const int* in_sizes, int n_in,
                              void* d_out, int out_size, void* d_ws, size_t ws_size,
                              hipStream_t stream) {
  const float* x  = (const float*)d_in[0];
  const float* wq = (const float*)d_in[1];
  const float* bq = (const float*)d_in[2];
  const float* wk = (const float*)d_in[3];
  const float* bk = (const float*)d_in[4];
  const float* wv = (const float*)d_in[5];
  const float* bv = (const float*)d_in[6];
  const float* wo = (const float*)d_in[7];
  const float* bo = (const float*)d_in[8];

  f16* W  = (f16*)d_ws;                     // 4 x 65536 f16 weights
  f16* Qd = W + 262144;                     // [B,N,256]
  f16* Kd = Qd + (size_t)CB * CN * CC;      // [B,N,256]
  f16* Vt = Kd + (size_t)CB * CN * CC;      // [B,256,N]

  prep_weights<<<256, 256, 0, stream>>>(wq, wk, wv, wo, W);
  qkv_kernel<<<512, 128, 0, stream>>>(x, W, W + 65536, W + 131072, bq, bk, bv, Qd, Kd, Vt);
  attn_kernel<<<512, 256, 0, stream>>>(Qd, Kd, Vt, W + 196608, bo, (float*)d_out);
}

// Round 18
// 322.497 us; speedup vs baseline: 1.0451x; 1.0451x over previous
//
#include <hip/hip_runtime.h>
#include <hip/hip_fp16.h>

typedef _Float16 f16;
typedef _Float16 f16x4 __attribute__((ext_vector_type(4)));
typedef _Float16 f16x8 __attribute__((ext_vector_type(8)));
typedef float f32x4 __attribute__((ext_vector_type(4)));
typedef float f32x16 __attribute__((ext_vector_type(16)));
typedef unsigned int u32;
typedef u32 u32x4 __attribute__((ext_vector_type(4)));

static constexpr int CB = 8;      // batch
static constexpr int CC = 256;    // channels = Co
static constexpr int CN = 4096;   // tokens = H*W

#define MFMA(a, b, c)   __builtin_amdgcn_mfma_f32_16x16x32_f16((a), (b), (c), 0, 0, 0)
#define MFMA32(a, b, c) __builtin_amdgcn_mfma_f32_32x32x16_f16((a), (b), (c), 0, 0, 0)

__device__ __forceinline__ void gll16(const void* g, void* l) {
  __builtin_amdgcn_global_load_lds(
      (const __attribute__((address_space(1))) unsigned int*)g,
      (__attribute__((address_space(3))) unsigned int*)l, 16, 0, 0);
}

// swap a's lanes 32-63 with b's lanes 0-31 (CDNA4 cross-half exchange)
__device__ __forceinline__ void plswap(u32& a, u32& b) {
  asm volatile("v_permlane32_swap_b32 %0, %1" : "+v"(a), "+v"(b));
}

__device__ __forceinline__ u32 pk(float lo, float hi) {
  auto h = __builtin_amdgcn_cvt_pkrtz(lo, hi);   // __fp16 ext_vector_type(2)
  return __builtin_bit_cast(u32, h);
}

__global__ __launch_bounds__(256) void prep_weights(const float* __restrict__ wq,
    const float* __restrict__ wk, const float* __restrict__ wv,
    const float* __restrict__ wo, f16* __restrict__ W) {
  int i = blockIdx.x * 256 + threadIdx.x;
  W[i]          = (f16)wq[i];
  W[65536 + i]  = (f16)wk[i];
  W[131072 + i] = (f16)wv[i];
  W[196608 + i] = (f16)wo[i];
}

// qkv v3 (verified): 32x32x16 MFMA, 32 n-rows per wave -> weight L2 traffic
// halves vs 16-row waves. Q/K: D[o][n]=mfma(W,x); V: D[n][o]=mfma(x,W).
__global__ __launch_bounds__(128) void qkv_kernel(const float* __restrict__ x,
    const f16* __restrict__ Wq, const f16* __restrict__ Wk, const f16* __restrict__ Wv,
    const float* __restrict__ bq, const float* __restrict__ bk, const float* __restrict__ bv,
    f16* __restrict__ Q, f16* __restrict__ K, f16* __restrict__ Vt) {
  __shared__ f16 xf[64][264];
  const int b  = blockIdx.x >> 6;
  const int n0 = (blockIdx.x & 63) << 6;
  const int t  = threadIdx.x;
  const float* xb = x + (size_t)b * CC * CN;
  {
    int c = t >> 4;                         // 0..7
    const int nn = (t & 15) << 2;
    #pragma unroll
    for (int pass = 0; pass < 32; ++pass, c += 8) {
      const float4 v = *(const float4*)(xb + (size_t)c * CN + n0 + nn);
      xf[nn + 0][c] = (f16)v.x;
      xf[nn + 1][c] = (f16)v.y;
      xf[nn + 2][c] = (f16)v.z;
      xf[nn + 3][c] = (f16)v.w;
    }
  }
  __syncthreads();
  const int w = t >> 6, l = t & 63, ln = l & 31, lh = l >> 5;

  // B-fragment of 32x32x16: lane row = ln (n), k = kt*16 + 8*lh + e
  f16x8 xff[16];
  #pragma unroll
  for (int kt = 0; kt < 16; ++kt)
    xff[kt] = *(const f16x8*)&xf[w * 32 + ln][kt * 16 + lh * 8];

  const size_t qkrow = ((size_t)b * CN + n0 + w * 32 + ln) * CC;

  #pragma unroll 1
  for (int mat = 0; mat < 2; ++mat) {
    const f16* W = mat ? Wk : Wq;
    const float* bias = mat ? bk : bq;
    f16* dst = mat ? K : Q;
    #pragma unroll 1
    for (int ot = 0; ot < 8; ot += 2) {
      f32x16 a0, a1;
      #pragma unroll
      for (int i = 0; i < 16; ++i) { a0[i] = 0.0f; a1[i] = 0.0f; }
      #pragma unroll
      for (int kt = 0; kt < 16; ++kt) {
        const f16x8 af0 = *(const f16x8*)&W[(size_t)(ot * 32 + ln) * CC + kt * 16 + lh * 8];
        a0 = MFMA32(af0, xff[kt], a0);
        const f16x8 af1 = *(const f16x8*)&W[(size_t)(ot * 32 + 32 + ln) * CC + kt * 16 + lh * 8];
        a1 = MFMA32(af1, xff[kt], a1);
      }
      #pragma unroll
      for (int rg = 0; rg < 4; ++rg) {
        const int o = ot * 32 + rg * 8 + lh * 4;
        const float4 b0 = *(const float4*)&bias[o];
        const float4 b1 = *(const float4*)&bias[o + 32];
        f16x4 h0, h1;
        h0[0] = (f16)(a0[rg * 4 + 0] + b0.x);
        h0[1] = (f16)(a0[rg * 4 + 1] + b0.y);
        h0[2] = (f16)(a0[rg * 4 + 2] + b0.z);
        h0[3] = (f16)(a0[rg * 4 + 3] + b0.w);
        h1[0] = (f16)(a1[rg * 4 + 0] + b1.x);
        h1[1] = (f16)(a1[rg * 4 + 1] + b1.y);
        h1[2] = (f16)(a1[rg * 4 + 2] + b1.z);
        h1[3] = (f16)(a1[rg * 4 + 3] + b1.w);
        *(f16x4*)&dst[qkrow + o]      = h0;
        *(f16x4*)&dst[qkrow + o + 32] = h1;
      }
    }
  }

  #pragma unroll 1
  for (int ot = 0; ot < 8; ot += 2) {
    f32x16 a0, a1;
    #pragma unroll
    for (int i = 0; i < 16; ++i) { a0[i] = 0.0f; a1[i] = 0.0f; }
    #pragma unroll
    for (int kt = 0; kt < 16; ++kt) {
      const f16x8 wf0 = *(const f16x8*)&Wv[(size_t)(ot * 32 + ln) * CC + kt * 16 + lh * 8];
      a0 = MFMA32(xff[kt], wf0, a0);
      const f16x8 wf1 = *(const f16x8*)&Wv[(size_t)(ot * 32 + 32 + ln) * CC + kt * 16 + lh * 8];
      a1 = MFMA32(xff[kt], wf1, a1);
    }
    const int o0 = ot * 32 + ln, o1 = o0 + 32;
    const float bv0 = bv[o0], bv1 = bv[o1];
    f16* v0 = &Vt[((size_t)b * CC + o0) * CN + n0 + w * 32];
    f16* v1 = &Vt[((size_t)b * CC + o1) * CN + n0 + w * 32];
    #pragma unroll
    for (int rg = 0; rg < 4; ++rg) {
      const int nn = rg * 8 + lh * 4;
      f16x4 h0, h1;
      #pragma unroll
      for (int j = 0; j < 4; ++j) {
        h0[j] = (f16)(a0[rg * 4 + j] + bv0);
        h1[j] = (f16)(a1[rg * 4 + j] + bv1);
      }
      *(f16x4*)&v0[nn] = h0;
      *(f16x4*)&v1[nn] = h1;
    }
  }
}

// flash attention v15: v11-exact main loop (272.9 us standalone) + fused
// out-projection epilogue on the qkv-v3 32x32x16 recipe (half the MFMA
// instructions, half the Wo L2 traffic, n-coalesced fp32 stores).
// Q,K [B,N,256], V^T [B,256,N], Wo [256,256] -> out [B,C,N] fp32
__global__ __launch_bounds__(256, 2) void attn_kernel(const f16* __restrict__ Q,
    const f16* __restrict__ K, const f16* __restrict__ Vt,
    const f16* __restrict__ Wo, const float* __restrict__ bo,
    float* __restrict__ out) {
  // SMEM (bytes):
  //   [0, 32768):     K frames: buf*16384 + ks*1024 (frag-linear, +16*l)
  //   [32768, 65536): V frames: 32768 + buf*16384 + f*1024
  //   [65536, 73728): P dbuf:   65536 + pbuf*4096 + g*2048 + fr*1024 (+16*l)
  //   [73728, 74240): ML per g: g*256 + {m[32] @0, l[32] @128}  (single-buffered)
  //   [74240, 75264): AF dbuf:  74240 + pbuf*512 + g*256 + {alpha[32] @0, flag @128}
  //   epilogue reuse: [0, 33792) = O-tile [64][264] f16 (2-way banks)
  __shared__ __align__(16) char SMEM[75264];

  const int bid = blockIdx.x;
  const int lb = ((bid & 7) << 6) | (bid >> 3);   // XCD swizzle: batch -> XCD
  const int b  = lb >> 6;
  const int q0 = (lb & 63) << 6;                  // 64 q-rows per block
  const int tid = threadIdx.x;
  const int w  = tid >> 6, l = tid & 63, ln = l & 31, lh = l >> 5;
  const int g  = w >> 1, hv = w & 1;              // q-group, o-half

  const f16* Qb = Q  + (size_t)b * CN * CC;
  const f16* Kb = K  + (size_t)b * CN * CC;
  const f16* Vb = Vt + (size_t)b * CC * CN;

  auto kfrm = [&](int buf, int ks) -> char* { return SMEM + (buf << 14) + (ks << 10); };
  auto vfrm = [&](int buf, int f)  -> char* { return SMEM + 32768 + (buf << 14) + (f << 10); };
  auto pfrm = [&](int pb, int fr)  -> char* { return SMEM + 65536 + (pb << 12) + (g << 11) + (fr << 10); };
  float* const MLm = (float*)(SMEM + 73728 + g * 256);
  float* const MLl = MLm + 32;
  auto AFa = [&](int pb) -> float* { return (float*)(SMEM + 74240 + (pb << 9) + (g << 8)); };

  auto stageK = [&](int buf, int kv0) {
    const f16* ksrc = Kb + (size_t)(kv0 + ln) * CC + (w * 4) * 16 + 8 * lh;
    #pragma unroll
    for (int j = 0; j < 4; ++j)
      gll16(ksrc + j * 16, kfrm(buf, w * 4 + j));
  };
  auto stageV = [&](int buf, int kv0) {
    #pragma unroll
    for (int p = 0; p < 2; ++p) {
      const int f = w * 4 + 2 * p;
      const f16* vsrc = Vb + (size_t)((f >> 1) * 32 + ln) * CN + kv0 + 8 * lh;
      gll16(vsrc,      vfrm(buf, f));
      gll16(vsrc + 16, vfrm(buf, f + 1));
    }
  };

  const int qrow = q0 + 32 * g + ln;
  f16x8 qf[16];
  #pragma unroll
  for (int ks = 0; ks < 16; ++ks)
    qf[ks] = *(const f16x8*)(Qb + (size_t)qrow * CC + ks * 16 + 8 * lh);

  f32x16 oacc[4];
  #pragma unroll
  for (int ot = 0; ot < 4; ++ot)
    #pragma unroll
    for (int i = 0; i < 16; ++i) oacc[ot][i] = 0.0f;

  auto pvstep = [&](int pb) {
    const float* af = AFa(pb);
    const float flag = af[32];
    if (flag != 0.0f) {
      #pragma unroll
      for (int r = 0; r < 16; ++r) {
        const float fr = af[(r & 3) + 8 * (r >> 2) + 4 * lh];
        #pragma unroll
        for (int ot = 0; ot < 4; ++ot) oacc[ot][r] *= fr;
      }
    }
    const f16x8 pa0 = *(const f16x8*)(pfrm(pb, 0) + l * 16);
    const f16x8 pa1 = *(const f16x8*)(pfrm(pb, 1) + l * 16);
    __builtin_amdgcn_s_setprio(1);
    #pragma unroll
    for (int ot = 0; ot < 4; ++ot) {
      const int f0 = 8 * hv + 2 * ot;
      const f16x8 v0 = *(const f16x8*)(vfrm(pb, f0) + l * 16);
      oacc[ot] = MFMA32(pa0, v0, oacc[ot]);
      const f16x8 v1 = *(const f16x8*)(vfrm(pb, f0 + 1) + l * 16);
      oacc[ot] = MFMA32(pa1, v1, oacc[ot]);
    }
    __builtin_amdgcn_s_setprio(0);
  };

  stageK(0, 0);
  __syncthreads();                                // K(0) ready

  #pragma unroll 1
  for (int it = 0; it < 128; ++it) {
    const int cur = it & 1, prv = cur ^ 1;
    if (it < 127) stageK(prv, (it + 1) * 32);     // K(it+1), drained at barrier
    stageV(cur, it * 32);                         // V(it), read next iter

    const bool own = (hv == cur);                 // wave-uniform (v11 exact)

    // owner: QK(it) — single 16-deep MFMA chain (v11 exact)
    f32x16 s;
    if (own) {
      #pragma unroll
      for (int i = 0; i < 16; ++i) s[i] = 0.0f;
      __builtin_amdgcn_s_setprio(1);
      #pragma unroll
      for (int ks = 0; ks < 16; ++ks) {
        const f16x8 kf = *(const f16x8*)(kfrm(cur, ks) + l * 16);
        s = MFMA32(kf, qf[ks], s);
      }
      __builtin_amdgcn_s_setprio(0);
    }

    // all waves: PV(it-1)
    if (it > 0) pvstep(prv);

    // owner: softmax(it) + publish P/alpha/m/l (v11 exact)
    if (own) {
      const float mprev = it ? MLm[ln] : -3e38f;
      const float lprev = it ? MLl[ln] : 0.0f;
      float mx8[8], mx4[4];
      #pragma unroll
      for (int i = 0; i < 8; ++i) mx8[i] = fmaxf(s[2 * i], s[2 * i + 1]);
      #pragma unroll
      for (int i = 0; i < 4; ++i) mx4[i] = fmaxf(mx8[2 * i], mx8[2 * i + 1]);
      float pmax = fmaxf(fmaxf(mx4[0], mx4[1]), fmaxf(mx4[2], mx4[3]));
      pmax = fmaxf(pmax, __shfl_xor(pmax, 32));
      const bool need = !__all(pmax - mprev <= 8.0f);   // defer-max (T13)
      const float mnew = need ? fmaxf(mprev, pmax) : mprev;
      float p[16];
      #pragma unroll
      for (int r = 0; r < 16; ++r) p[r] = __expf(s[r] - mnew);
      float sm8[8], sm4[4];
      #pragma unroll
      for (int i = 0; i < 8; ++i) sm8[i] = p[2 * i] + p[2 * i + 1];
      #pragma unroll
      for (int i = 0; i < 4; ++i) sm4[i] = sm8[2 * i] + sm8[2 * i + 1];
      float psum = (sm4[0] + sm4[1]) + (sm4[2] + sm4[3]);
      psum += __shfl_xor(psum, 32);
      float alpha = 1.0f, lnew;
      if (need) { alpha = __expf(mprev - mnew); lnew = lprev * alpha + psum; }
      else      { lnew = lprev + psum; }
      if (l < 32) {
        MLm[ln] = mnew;
        MLl[ln] = lnew;
        float* af = AFa(cur);
        af[ln] = alpha;
        if (ln == 0) af[32] = need ? 1.0f : 0.0f;
      }
      u32 pw[8];
      #pragma unroll
      for (int i = 0; i < 8; ++i) pw[i] = pk(p[2 * i], p[2 * i + 1]);
      plswap(pw[0], pw[2]); plswap(pw[1], pw[3]);
      plswap(pw[4], pw[6]); plswap(pw[5], pw[7]);
      *(u32x4*)(pfrm(cur, 0) + l * 16) = u32x4{pw[0], pw[1], pw[2], pw[3]};
      *(u32x4*)(pfrm(cur, 1) + l * 16) = u32x4{pw[4], pw[5], pw[6], pw[7]};
    }
    __syncthreads();   // drains K(it+1)/V(it); publishes P/ML/AF(it)
  }

  // epilogue part 1: PV(127) (buffers pb=1), grab 1/l values
  pvstep(1);
  float invv[16];
  #pragma unroll
  for (int r = 0; r < 16; ++r)
    invv[r] = 1.0f / MLl[(r & 3) + 8 * (r >> 2) + 4 * lh];
  __syncthreads();                                // everyone done with K/ML regions

  // epilogue part 2: normalized O-tile -> LDS [64][264] f16
  f16* const OT = (f16*)SMEM;
  #pragma unroll
  for (int r = 0; r < 16; ++r) {
    const int q = (r & 3) + 8 * (r >> 2) + 4 * lh;
    const int qq = 32 * g + q;
    #pragma unroll
    for (int ot = 0; ot < 4; ++ot)
      OT[qq * 264 + 128 * hv + ot * 32 + ln] = (f16)(oacc[ot][r] * invv[r]);
  }
  __syncthreads();

  // epilogue part 3: fused out-projection on the qkv-v3 32x32x16 recipe.
  // wave w: n-group rgn = w>>1 (32 rows), c-half ch = w&1 (128 cols).
  // D[c][n] = mfma32(A = Wo rows c, B = O rows n); 64 MFMA32/wave.
  {
    const int rgn = w >> 1, ch = w & 1;
    f32x16 acc[4];
    #pragma unroll
    for (int ot = 0; ot < 4; ++ot)
      #pragma unroll
      for (int i = 0; i < 16; ++i) acc[ot][i] = 0.0f;
    #pragma unroll
    for (int kt = 0; kt < 16; ++kt) {
      const f16x8 bf = *(const f16x8*)&OT[(rgn * 32 + ln) * 264 + kt * 16 + lh * 8];
      #pragma unroll
      for (int ot = 0; ot < 4; ++ot) {
        const f16x8 af = *(const f16x8*)&Wo[(size_t)(ch * 128 + ot * 32 + ln) * CC + kt * 16 + lh * 8];
        acc[ot] = MFMA32(af, bf, acc[ot]);
      }
    }
    // store: c = ch*128 + ot*32 + rg*8 + 4*lh + j, n = q0 + rgn*32 + ln (coalesced)
    const size_t nidx = q0 + rgn * 32 + ln;
    #pragma unroll
    for (int ot = 0; ot < 4; ++ot) {
      #pragma unroll
      for (int rg = 0; rg < 4; ++rg) {
        const int c0 = ch * 128 + ot * 32 + rg * 8 + 4 * lh;
        const float4 b4 = *(const float4*)&bo[c0];
        float* op = out + ((size_t)b * CC + c0) * CN + nidx;
        op[0 * (size_t)CN] = acc[ot][rg * 4 + 0] + b4.x;
        op[1 * (size_t)CN] = acc[ot][rg * 4 + 1] + b4.y;
        op[2 * (size_t)CN] = acc[ot][rg * 4 + 2] + b4.z;
        op[3 * (size_t)CN] = acc[ot][rg * 4 + 3] + b4.w;
      }
    }
  }
}

extern "C" void kernel_launch(void* const* d_in, const int* in_sizes, int n_in,
                              void* d_out, int out_size, void* d_ws, size_t ws_size,
                              hipStream_t stream) {
  const float* x  = (const float*)d_in[0];
  const float* wq = (const float*)d_in[1];
  const float* bq = (const float*)d_in[2];
  const float* wk = (const float*)d_in[3];
  const float* bk = (const float*)d_in[4];
  const float* wv = (const float*)d_in[5];
  const float* bv = (const float*)d_in[6];
  const float* wo = (const float*)d_in[7];
  const float* bo = (const float*)d_in[8];

  f16* W  = (f16*)d_ws;                     // 4 x 65536 f16 weights
  f16* Qd = W + 262144;                     // [B,N,256]
  f16* Kd = Qd + (size_t)CB * CN * CC;      // [B,N,256]
  f16* Vt = Kd + (size_t)CB * CN * CC;      // [B,256,N]

  prep_weights<<<256, 256, 0, stream>>>(wq, wk, wv, wo, W);
  qkv_kernel<<<512, 128, 0, stream>>>(x, W, W + 65536, W + 131072, bq, bk, bv, Qd, Kd, Vt);
  attn_kernel<<<512, 256, 0, stream>>>(Qd, Kd, Vt, W + 196608, bo, (float*)d_out);
}